// Round 23
// baseline (42.785 us; speedup 1.0000x reference)
//
#include <hip/hip_runtime.h>
#include <math.h>

// Chamfer loss via MFMA — SHARED-MATRIX version (round 23).
// Key identity: with bf16-split packing, (-2x)_h == -2*x_h EXACTLY (mul by
// 2 is exponent-exact), so the dir-0 tile matrix d2[i][j] is numerically
// the same data dir-1 needs. One sweep computes BOTH: row-min (pred->targ)
// via the r17 fold, col-min (targ->pred) via per-lane min3 chains + a
// 32KB LDS colbuf reduced across the block. Halves MFMA count (524K->262K),
// B-fetch, pack work, and s_nop stalls vs r17 (best, 38.4us).
// Math/packing/layout verified r12-r22 (absmax 0).

typedef __attribute__((ext_vector_type(8)))  short  short8;
typedef __attribute__((ext_vector_type(16))) float  f32x16;

#define YS      8     // col-chunk splits (cols per block = M/YS = 1024)
#define RPB     256   // rows per block = 4 waves * 64 (2 strips of 32)

#define MFMA2(da, db, A, B0, B1) \
    asm("v_mfma_f32_32x32x16_bf16 %0, %2, %3, 0\n\t" \
        "v_mfma_f32_32x32x16_bf16 %1, %2, %4, 0\n\t" \
        "s_nop 7\n\t" \
        "s_nop 7" \
        : "=&v"(da), "=&v"(db) \
        : "v"(A), "v"(B0), "v"(B1))

static __device__ __forceinline__ float min3f(float a, float b, float c) {
    float d;
    asm("v_min3_f32 %0, %1, %2, %3" : "=v"(d) : "v"(a), "v"(b), "v"(c));
    return d;
}

static inline int roundup_h(int v, int a) { return (v + a - 1) / a * a; }

static __device__ __forceinline__ unsigned short f2bf(float f) {
    union { float f; unsigned int u; } v; v.f = f;
    unsigned int r = v.u + 0x7FFFu + ((v.u >> 16) & 1u);  // RNE
    return (unsigned short)(r >> 16);
}
static __device__ __forceinline__ float bf2f(unsigned short s) {
    union { unsigned int u; float f; } v; v.u = ((unsigned int)s) << 16;
    return v.f;
}
static __device__ __forceinline__ unsigned int pk2(unsigned short lo,
                                                   unsigned short hi) {
    return (unsigned int)lo | ((unsigned int)hi << 16);
}

// all-reduce min over each 32-lane group: 4 DPP levels (VALU) + 1 swizzle
static __device__ __forceinline__ float allmin32(float v) {
    union { float f; int i; } u, t;
    u.f = v;
    t.i = __builtin_amdgcn_update_dpp(u.i, u.i, 0xB1, 0xF, 0xF, false);  // xor1
    u.f = fminf(u.f, t.f);
    t.i = __builtin_amdgcn_update_dpp(u.i, u.i, 0x4E, 0xF, 0xF, false);  // xor2
    u.f = fminf(u.f, t.f);
    t.i = __builtin_amdgcn_update_dpp(u.i, u.i, 0x124, 0xF, 0xF, false); // ror4
    u.f = fminf(u.f, t.f);
    t.i = __builtin_amdgcn_update_dpp(u.i, u.i, 0x128, 0xF, 0xF, false); // ror8
    u.f = fminf(u.f, t.f);
    t.i = __builtin_amdgcn_ds_swizzle(u.i, 0x401F);                      // xor16
    u.f = fminf(u.f, t.f);
    return u.f;
}

// A-pack for pred rows, B-pack for targ cols (only what the single sweep
// needs). Layouts verified r14-r22.
__global__ __launch_bounds__(256) void pack_kernel(
    const float* __restrict__ pred, const float* __restrict__ targ,
    int B, int N, int M, int NpadP, int NpadT,
    unsigned short* __restrict__ aP, unsigned short* __restrict__ bT)
{
    const int padmax = (NpadP > NpadT) ? NpadP : NpadT;
    const int gid = blockIdx.x * 256 + threadIdx.x;
    if (gid >= B * padmax) return;
    const int b = gid / padmax, i = gid - b * padmax;

    const unsigned short ONE = 0x3F80;

    if (i < NpadP) {   // pred -> A-pattern
        const float* src = pred + ((size_t)b * N + min(i, N - 1)) * 3;
        unsigned short* A = aP + ((size_t)b * NpadP + i) * 16;
        const float xs[3] = {src[0], src[1], src[2]};
        const float n2 = xs[0]*xs[0] + xs[1]*xs[1] + xs[2]*xs[2];
        unsigned short th[3], tl[3];
        #pragma unroll
        for (int c = 0; c < 3; ++c) {
            const float t = -2.0f * xs[c];
            th[c] = f2bf(t); tl[c] = f2bf(t - bf2f(th[c]));
        }
        const unsigned short n2h = f2bf(n2);
        const unsigned short n2l = f2bf(n2 - bf2f(n2h));
        uint4 alo, ahi;
        alo.x = pk2(th[0], th[1]); alo.y = pk2(th[2], tl[0]);
        alo.z = pk2(tl[1], tl[2]); alo.w = pk2(th[0], th[1]);
        ahi.x = pk2(th[2], tl[0]); ahi.y = pk2(tl[1], tl[2]);
        ahi.z = pk2(ONE,  ONE);    ahi.w = pk2(n2h,  n2l);
        *(uint4*)(A) = alo;  *(uint4*)(A + 8) = ahi;
    }

    if (i < NpadT) {   // targ -> B-pattern, [tile][khalf][point] order
        const float* src = targ + ((size_t)b * M + min(i, M - 1)) * 3;
        unsigned short* Bk = bT + (size_t)b * NpadT * 16;
        const float xs[3] = {src[0], src[1], src[2]};
        const float n2 = xs[0]*xs[0] + xs[1]*xs[1] + xs[2]*xs[2];
        unsigned short yh[3], yl[3];
        #pragma unroll
        for (int c = 0; c < 3; ++c) {
            yh[c] = f2bf(xs[c]); yl[c] = f2bf(xs[c] - bf2f(yh[c]));
        }
        const unsigned short n2h = f2bf(n2);
        const unsigned short n2l = f2bf(n2 - bf2f(n2h));
        uint4 blo, bhi;
        blo.x = pk2(yh[0], yh[1]); blo.y = pk2(yh[2], yh[0]);
        blo.z = pk2(yh[1], yh[2]); blo.w = pk2(yl[0], yl[1]);
        bhi.x = pk2(yl[2], yl[0]); bhi.y = pk2(yl[1], yl[2]);
        bhi.z = pk2(n2h,  n2l);    bhi.w = pk2(ONE,  ONE);
        const size_t tb = (size_t)(i >> 5) * 64 + (i & 31);   // 16B units
        *(uint4*)(Bk + tb * 8)        = blo;                   // khalf 0
        *(uint4*)(Bk + (tb + 32) * 8) = bhi;                   // khalf 1
    }
}

// Single shared-matrix sweep. Block = (b, js, sp). 4 waves; wave w owns
// rows [sp*256 + w*64, +64) (2 strips). Cols chunk js (nt0*32 cols).
// Per tile-pair: 2 MFMA2 + row folds + col chains; col partials to LDS,
// block-reduced to colpart. Row partials via DPP epilogue to rowpart.
__global__ __launch_bounds__(256, 4) void mfma_sweep(
    const unsigned short* __restrict__ aP, const unsigned short* __restrict__ bT,
    int B, int N, int M, int NpadP, int NpadT, int NpadMax, int SP,
    float* __restrict__ rowpart, float* __restrict__ colpart)
{
    const int tid  = threadIdx.x;
    const int w    = tid >> 6;
    const int lane = tid & 63;
    const int lc   = lane & 31, h = lane >> 5;

    int t = blockIdx.x;
    const int sp  = t % SP;  t /= SP;
    const int js  = t % YS;  t /= YS;
    const int b   = t;

    if (sp * RPB >= NpadP) return;          // block-uniform

    const int TM  = NpadT / 32;             // mult of 8 -> nt0 exact
    const int nt0 = TM / YS;
    const int t0  = js * nt0;

    __shared__ float colbuf[8][1024];       // 32 KB: [wave*2+h][col in chunk]

    // A-frags (loop-invariant): row = lane&31, k = (lane>>5)*8 + e
    const int row0 = sp * RPB + w * 64;
    const size_t abase = ((size_t)b * NpadP + row0 + lc) * 16 + (size_t)h * 8;
    const short8 a0 = *reinterpret_cast<const short8*>(aP + abase);
    const short8 a1 = *reinterpret_cast<const short8*>(aP + abase + 32 * 16);

    f32x16 rm0, rm1;
    #pragma unroll
    for (int r = 0; r < 16; ++r) {
        rm0[r] = __builtin_inff(); rm1[r] = __builtin_inff();
    }

    // B-frag stream: tile j at yp + j*512 shorts (tile stride = 1KB)
    const unsigned short* yp =
        bT + (size_t)b * NpadT * 16 + (size_t)t0 * 512 + (size_t)lane * 8;
    short8 c0 = *reinterpret_cast<const short8*>(yp);
    short8 c1 = *reinterpret_cast<const short8*>(yp + 512);

    for (int j = 0; j < nt0; j += 2) {
        const short8 n0 = *reinterpret_cast<const short8*>(yp + 1024);
        const short8 n1 = *reinterpret_cast<const short8*>(yp + 1536);
        yp += 1024;
        __builtin_amdgcn_sched_barrier(0);   // keep prefetch issued early
        float cmA, cmB;                      // col chains: tile j, tile j+1
        {   // strip 0
            f32x16 da, db;
            MFMA2(da, db, a0, c0, c1);
            #pragma unroll
            for (int r = 0; r < 16; ++r)
                rm0[r] = min3f(da[r], db[r], rm0[r]);
            cmA = min3f(da[0], da[1], da[2]);
            cmA = min3f(cmA, da[3],  da[4]);
            cmA = min3f(cmA, da[5],  da[6]);
            cmA = min3f(cmA, da[7],  da[8]);
            cmA = min3f(cmA, da[9],  da[10]);
            cmA = min3f(cmA, da[11], da[12]);
            cmA = min3f(cmA, da[13], da[14]);
            cmA = min3f(cmA, da[15], cmA);
            cmB = min3f(db[0], db[1], db[2]);
            cmB = min3f(cmB, db[3],  db[4]);
            cmB = min3f(cmB, db[5],  db[6]);
            cmB = min3f(cmB, db[7],  db[8]);
            cmB = min3f(cmB, db[9],  db[10]);
            cmB = min3f(cmB, db[11], db[12]);
            cmB = min3f(cmB, db[13], db[14]);
            cmB = min3f(cmB, db[15], cmB);
        }
        {   // strip 1
            f32x16 da, db;
            MFMA2(da, db, a1, c0, c1);
            #pragma unroll
            for (int r = 0; r < 16; ++r)
                rm1[r] = min3f(da[r], db[r], rm1[r]);
            cmA = min3f(cmA, da[0],  da[1]);
            cmA = min3f(cmA, da[2],  da[3]);
            cmA = min3f(cmA, da[4],  da[5]);
            cmA = min3f(cmA, da[6],  da[7]);
            cmA = min3f(cmA, da[8],  da[9]);
            cmA = min3f(cmA, da[10], da[11]);
            cmA = min3f(cmA, da[12], da[13]);
            cmA = min3f(cmA, da[14], da[15]);
            cmB = min3f(cmB, db[0],  db[1]);
            cmB = min3f(cmB, db[2],  db[3]);
            cmB = min3f(cmB, db[4],  db[5]);
            cmB = min3f(cmB, db[6],  db[7]);
            cmB = min3f(cmB, db[8],  db[9]);
            cmB = min3f(cmB, db[10], db[11]);
            cmB = min3f(cmB, db[12], db[13]);
            cmB = min3f(cmB, db[14], db[15]);
        }
        // col partials: slot = w*2+h, cols j*32+lc and (j+1)*32+lc
        colbuf[w * 2 + h][j * 32 + lc] = cmA;
        if (j + 1 < nt0) colbuf[w * 2 + h][(j + 1) * 32 + lc] = cmB;
        c0 = n0; c1 = n1;
    }

    // ---- row epilogue: per-row min over 32 cols (DPP), store raw minima.
    // D layout: col=lane&31, row=(r&3)+8*(r>>2)+4*(lane>>5)
    const size_t outb = ((size_t)b * YS + js) * (size_t)NpadMax;
    #pragma unroll
    for (int r = 0; r < 16; ++r) {
        const float v0 = allmin32(rm0[r]);
        const float v1 = allmin32(rm1[r]);
        if (lc == 0) {
            const int rr = (r & 3) + 8 * (r >> 2) + 4 * h;
            const int ra = row0 + rr, rb = row0 + 32 + rr;
            if (ra < N) rowpart[outb + ra] = v0;
            if (rb < N) rowpart[outb + rb] = v1;
        }
    }

    // ---- col epilogue: min over the 8 slots, store raw minima ----
    __syncthreads();
    const int nc = nt0 * 32;
    const size_t coutb = ((size_t)b * SP + sp) * (size_t)NpadMax;
    for (int c = tid; c < nc; c += 256) {
        float m = colbuf[0][c];
        #pragma unroll
        for (int s = 1; s < 8; ++s) m = fminf(m, colbuf[s][c]);
        const int gcol = t0 * 32 + c;
        if (gcol < M) colpart[coutb + gcol] = m;
    }
}

__global__ __launch_bounds__(256) void combine_kernel(
    const float* __restrict__ rowpart, const float* __restrict__ colpart,
    int B, int N, int M, int NpadMax, int SP,
    float invBN, float invBM, float* __restrict__ partial)
{
    const int tid = threadIdx.x;
    const int per = B * NpadMax;
    const int tot = 2 * per;
    float acc = 0.f;
    for (int idx = blockIdx.x * 256 + tid; idx < tot; idx += gridDim.x * 256) {
        const int half = idx / per;
        const int rem  = idx - half * per;
        const int b    = rem / NpadMax;
        const int p    = rem - b * NpadMax;
        if (half == 0) {          // rows: pred -> targ
            if (p >= N) continue;
            float m = __builtin_inff();
            #pragma unroll
            for (int js = 0; js < YS; ++js)
                m = fminf(m, rowpart[((size_t)b * YS + js) * NpadMax + p]);
            acc += fmaxf(m, 0.f) * invBN;
        } else {                  // cols: targ -> pred
            if (p >= M) continue;
            float m = __builtin_inff();
            for (int s = 0; s < SP; ++s)
                m = fminf(m, colpart[((size_t)b * SP + s) * NpadMax + p]);
            acc += fmaxf(m, 0.f) * invBM;
        }
    }
    __shared__ float sb[256];
    sb[tid] = acc; __syncthreads();
    for (int off2 = 128; off2 > 0; off2 >>= 1) {
        if (tid < off2) sb[tid] += sb[tid + off2];
        __syncthreads();
    }
    if (tid == 0) partial[blockIdx.x] = sb[0];
}

__global__ void finalize_kernel(const float* __restrict__ partial, int np,
                                const float* __restrict__ fbpp, int Bf,
                                const void* __restrict__ lamp,
                                float* __restrict__ out)
{
    __shared__ float sb[256];
    const int tid = threadIdx.x;
    float acc = 0.f;
    for (int i = tid; i < np; i += 256) acc += partial[i];
    sb[tid] = acc;
    __syncthreads();
    for (int off = 128; off > 0; off >>= 1) {
        if (tid < off) sb[tid] += sb[tid + off];
        __syncthreads();
    }
    if (tid == 0) {
        const int li = *(const int*)lamp;
        const float lam = (li >= -1000000 && li <= 1000000)
                            ? (float)li : *(const float*)lamp;
        float fm = 0.f;
        for (int i = 0; i < Bf; ++i) fm += fbpp[i];
        fm /= (float)Bf;
        out[0] = sb[0] + lam * fm;
    }
}

extern "C" void kernel_launch(void* const* d_in, const int* in_sizes, int n_in,
                              void* d_out, int out_size, void* d_ws, size_t ws_size,
                              hipStream_t stream) {
    const float* pred = (const float*)d_in[0];
    const float* targ = (const float*)d_in[1];
    const float* fbpp = (const float*)d_in[2];
    const void*  lamp = d_in[3];

    const int B = in_sizes[2];
    const int N = in_sizes[0] / (3 * B);
    const int M = in_sizes[1] / (3 * B);
    const int NpadP = roundup_h(N, RPB);
    const int NpadT = roundup_h(M, RPB);
    const int NpadMax = (NpadP > NpadT) ? NpadP : NpadT;
    const int SP = NpadP / RPB;

    // ---- workspace (+8KB slack after each pack for prefetch OOB) ----
    size_t o = 0;
    auto take = [&](size_t bytes) {
        size_t r = o; o += (bytes + 255) & ~(size_t)255; return r;
    };
    unsigned short* aP = (unsigned short*)((char*)d_ws +
                         take((size_t)B * NpadP * 32 + 8192));
    unsigned short* bT = (unsigned short*)((char*)d_ws +
                         take((size_t)B * NpadT * 32 + 8192));
    float* rowpart = (float*)((char*)d_ws +
                     take((size_t)B * YS * NpadMax * sizeof(float)));
    float* colpart = (float*)((char*)d_ws +
                     take((size_t)B * SP * NpadMax * sizeof(float)));
    float* partial = (float*)((char*)d_ws + take(256 * sizeof(float)));
    (void)ws_size;

    // ---- 1) pack pred->A, targ->B ----
    pack_kernel<<<(B * NpadMax + 255) / 256, 256, 0, stream>>>(
        pred, targ, B, N, M, NpadP, NpadT, aP, bT);

    // ---- 2) single shared-matrix sweep ----
    const int blocks = B * YS * SP;    // 1024 for 8192^2
    mfma_sweep<<<blocks, 256, 0, stream>>>(
        aP, bT, B, N, M, NpadP, NpadT, NpadMax, SP, rowpart, colpart);

    // ---- 3) combine splits + clamp + weighted sum ----
    combine_kernel<<<256, 256, 0, stream>>>(
        rowpart, colpart, B, N, M, NpadMax, SP,
        1.f / ((float)B * (float)N), 1.f / ((float)B * (float)M), partial);

    // ---- 4) finalize ----
    finalize_kernel<<<1, 256, 0, stream>>>(partial, 256, fbpp, B, lamp,
                                           (float*)d_out);
}

// Round 24
// 38.641 us; speedup vs baseline: 1.1072x; 1.1072x over previous
//
#include <hip/hip_runtime.h>
#include <math.h>

// Chamfer loss via MFMA — FINAL (revert to round-17, the measured best:
// 38.40us, absmax 0). Ten structural variants (r14-r23) spanning 2x
// differences in MFMA count, LDS traffic, VALU count, fetch traffic and
// occupancy all land in 38.4-42.8us; r19's ablation showed full ~= MFMA-only
// ~= fold-only with no pipe >60% busy at effective clock ~750MHz. The
// residual is a fixed environmental floor (DVFS-depressed clock + 4-launch
// dispatch overhead), not a pipe limit. This file is the best-known kernel:
// bf16-split K-packed d2 via one v_mfma_f32_32x32x16_bf16 per 32x32 tile
// (k0-11: split cross terms, k12-13: |y|^2, k14-15: |x|^2), direct-global
// B-stream, asm MFMA2 (arch-VGPR, early-clobber, s_nop hazard guard),
// v_min3 folds, DPP+swizzle row-min epilogue.

typedef __attribute__((ext_vector_type(8)))  short  short8;
typedef __attribute__((ext_vector_type(16))) float  f32x16;

#define YS      4     // j-range splits per (dir,b)
#define RPB     256   // rows per block = 4 waves * 64 (2 strips/wave)

// 2 MFMAs (one A-strip x 2 j-tiles), C=0 inline, early-clobber outputs,
// 16 cycles of s_nop before any VALU read of the results.
#define MFMA2(da, db, A, B0, B1) \
    asm("v_mfma_f32_32x32x16_bf16 %0, %2, %3, 0\n\t" \
        "v_mfma_f32_32x32x16_bf16 %1, %2, %4, 0\n\t" \
        "s_nop 7\n\t" \
        "s_nop 7" \
        : "=&v"(da), "=&v"(db) \
        : "v"(A), "v"(B0), "v"(B1))

// single-instruction 3-input min (no canonicalize; inputs finite)
static __device__ __forceinline__ float min3f(float a, float b, float c) {
    float d;
    asm("v_min3_f32 %0, %1, %2, %3" : "=v"(d) : "v"(a), "v"(b), "v"(c));
    return d;
}

static inline int roundup_h(int v, int a) { return (v + a - 1) / a * a; }

static __device__ __forceinline__ unsigned short f2bf(float f) {
    union { float f; unsigned int u; } v; v.f = f;
    unsigned int r = v.u + 0x7FFFu + ((v.u >> 16) & 1u);  // RNE
    return (unsigned short)(r >> 16);
}
static __device__ __forceinline__ float bf2f(unsigned short s) {
    union { unsigned int u; float f; } v; v.u = ((unsigned int)s) << 16;
    return v.f;
}
static __device__ __forceinline__ unsigned int pk2(unsigned short lo,
                                                   unsigned short hi) {
    return (unsigned int)lo | ((unsigned int)hi << 16);
}

// all-reduce min over each 32-lane group: 4 DPP levels (VALU) + 1 swizzle
static __device__ __forceinline__ float allmin32(float v) {
    union { float f; int i; } u, t;
    u.f = v;
    t.i = __builtin_amdgcn_update_dpp(u.i, u.i, 0xB1, 0xF, 0xF, false);  // xor1
    u.f = fminf(u.f, t.f);
    t.i = __builtin_amdgcn_update_dpp(u.i, u.i, 0x4E, 0xF, 0xF, false);  // xor2
    u.f = fminf(u.f, t.f);
    t.i = __builtin_amdgcn_update_dpp(u.i, u.i, 0x124, 0xF, 0xF, false); // ror4
    u.f = fminf(u.f, t.f);
    t.i = __builtin_amdgcn_update_dpp(u.i, u.i, 0x128, 0xF, 0xF, false); // ror8
    u.f = fminf(u.f, t.f);
    t.i = __builtin_amdgcn_ds_swizzle(u.i, 0x401F);                      // xor16
    u.f = fminf(u.f, t.f);
    return u.f;
}

// A layout: per point i: 16 bf16 (two 16B halves, khalf h at +8 shorts).
// B layout: per (b): [tile][khalf][point] 16B units (tile=i>>5, p=i&31)
//  -> lane l's direct global read at tile*1024B + l*16B yields
//     point=l&31, khalf=l>>5, exactly the MFMA B-fragment.
__global__ __launch_bounds__(256) void pack_kernel(
    const float* __restrict__ pred, const float* __restrict__ targ,
    int B, int N, int M, int NpadP, int NpadT,
    unsigned short* __restrict__ aP, unsigned short* __restrict__ bP,
    unsigned short* __restrict__ aT, unsigned short* __restrict__ bT)
{
    const int padmax = (NpadP > NpadT) ? NpadP : NpadT;
    const int gid = blockIdx.x * 256 + threadIdx.x;
    if (gid >= B * padmax) return;
    const int b = gid / padmax, i = gid - b * padmax;

    for (int cloud = 0; cloud < 2; ++cloud) {
        const int cnt  = cloud ? M : N;
        const int npad = cloud ? NpadT : NpadP;
        if (i >= npad) continue;
        // padding duplicates the last point: harmless for min reductions
        const float* src = (cloud ? targ : pred) +
                           ((size_t)b * cnt + min(i, cnt - 1)) * 3;
        unsigned short* A  = (cloud ? aT : aP) + ((size_t)b * npad + i) * 16;
        unsigned short* Bk = (cloud ? bT : bP) + (size_t)b * npad * 16;

        const float xs[3] = {src[0], src[1], src[2]};
        const float n2 = xs[0]*xs[0] + xs[1]*xs[1] + xs[2]*xs[2];
        unsigned short th[3], tl[3], yh[3], yl[3];
        #pragma unroll
        for (int c = 0; c < 3; ++c) {
            const float t = -2.0f * xs[c];
            th[c] = f2bf(t);     tl[c] = f2bf(t - bf2f(th[c]));
            yh[c] = f2bf(xs[c]); yl[c] = f2bf(xs[c] - bf2f(yh[c]));
        }
        const unsigned short n2h = f2bf(n2);
        const unsigned short n2l = f2bf(n2 - bf2f(n2h));
        const unsigned short ONE = 0x3F80;

        uint4 alo, ahi, blo, bhi;
        alo.x = pk2(th[0], th[1]); alo.y = pk2(th[2], tl[0]);
        alo.z = pk2(tl[1], tl[2]); alo.w = pk2(th[0], th[1]);
        ahi.x = pk2(th[2], tl[0]); ahi.y = pk2(tl[1], tl[2]);
        ahi.z = pk2(ONE,  ONE);    ahi.w = pk2(n2h,  n2l);
        blo.x = pk2(yh[0], yh[1]); blo.y = pk2(yh[2], yh[0]);
        blo.z = pk2(yh[1], yh[2]); blo.w = pk2(yl[0], yl[1]);
        bhi.x = pk2(yl[2], yl[0]); bhi.y = pk2(yl[1], yl[2]);
        bhi.z = pk2(n2h,  n2l);    bhi.w = pk2(ONE,  ONE);

        *(uint4*)(A)     = alo;  *(uint4*)(A + 8) = ahi;
        const size_t tb = (size_t)(i >> 5) * 64 + (i & 31);   // 16B units
        *(uint4*)(Bk + tb * 8)        = blo;                   // khalf 0
        *(uint4*)(Bk + (tb + 32) * 8) = bhi;                   // khalf 1
    }
}

// Block = (dir, b, js, row-block of 256). 4 waves; wave w owns 64 rows
// (2 MFMA strips). B-fragments read DIRECTLY from global (L1/L2-resident,
// coalesced 1KB wave-loads), 1-deep prefetch. No LDS, no barriers.
// Inner (per 2 y-tiles): 2 loads + 2x(MFMA2 + 16 asm v_min3).
__global__ __launch_bounds__(256, 4) void mfma_sweep(
    const unsigned short* __restrict__ aP, const unsigned short* __restrict__ bP,
    const unsigned short* __restrict__ aT, const unsigned short* __restrict__ bT,
    int B, int N, int M, int NpadP, int NpadT, int NpadMax,
    float* __restrict__ rowpart)
{
    const int tid  = threadIdx.x;
    const int w    = tid >> 6;
    const int lane = tid & 63;
    const int lc   = lane & 31, h = lane >> 5;

    const int SP = NpadMax / RPB;
    int t = blockIdx.x;
    const int sp  = t % SP;  t /= SP;
    const int js  = t % YS;  t /= YS;
    const int b   = t % B;   t /= B;
    const int dir = t;

    const unsigned short* Xp = (dir == 0) ? aP : aT;
    const unsigned short* Yp = (dir == 0) ? bT : bP;
    const int NpadX = (dir == 0) ? NpadP : NpadT;
    const int NpadY = (dir == 0) ? NpadT : NpadP;
    const int Nx    = (dir == 0) ? N : M;
    if (sp * RPB >= NpadX) return;          // block-uniform

    // NpadY is a multiple of 256 -> TM mult of 8 -> nt0 = TM/YS exact
    const int TM  = NpadY / 32;
    const int nt0 = TM / YS;
    const int t0  = js * nt0;

    // A-frags (loop-invariant): row = lane&31, k = (lane>>5)*8 + e
    const int row0 = sp * RPB + w * 64;
    const size_t abase = ((size_t)b * NpadX + row0 + lc) * 16 + (size_t)h * 8;
    const short8 a0 = *reinterpret_cast<const short8*>(Xp + abase);
    const short8 a1 = *reinterpret_cast<const short8*>(Xp + abase + 32 * 16);

    f32x16 rm0, rm1;
    #pragma unroll
    for (int r = 0; r < 16; ++r) {
        rm0[r] = __builtin_inff(); rm1[r] = __builtin_inff();
    }

    // B-frag stream: tile j at yp + j*512 shorts (tile stride = 1KB)
    const unsigned short* yp =
        Yp + (size_t)b * NpadY * 16 + (size_t)t0 * 512 + (size_t)lane * 8;
    short8 c0 = *reinterpret_cast<const short8*>(yp);
    short8 c1 = *reinterpret_cast<const short8*>(yp + 512);

    for (int j = 0; j < nt0; j += 2) {
        // prefetch next pair (last iter reads <=2 tiles past the chunk:
        // covered by the 8KB slack after each pack buffer)
        const short8 n0 = *reinterpret_cast<const short8*>(yp + 1024);
        const short8 n1 = *reinterpret_cast<const short8*>(yp + 1536);
        yp += 1024;
        __builtin_amdgcn_sched_barrier(0);   // keep prefetch issued early
        {   // strip 0 (transient 32-reg D, then fold)
            f32x16 da, db;
            MFMA2(da, db, a0, c0, c1);
            #pragma unroll
            for (int r = 0; r < 16; ++r)
                rm0[r] = min3f(da[r], db[r], rm0[r]);   // 1 instr each
        }
        {   // strip 1
            f32x16 da, db;
            MFMA2(da, db, a1, c0, c1);
            #pragma unroll
            for (int r = 0; r < 16; ++r)
                rm1[r] = min3f(da[r], db[r], rm1[r]);
        }
        c0 = n0; c1 = n1;
    }

    // per-row min over 32 cols (DPP+swizzle all-reduce), then store.
    // D layout: col=lane&31, row=(r&3)+8*(r>>2)+4*(lane>>5)
    const size_t outb = (((size_t)dir * B + b) * YS + js) * (size_t)NpadMax;
    #pragma unroll
    for (int r = 0; r < 16; ++r) {
        const float v0 = allmin32(rm0[r]);
        const float v1 = allmin32(rm1[r]);
        if (lc == 0) {
            const int rr = (r & 3) + 8 * (r >> 2) + 4 * h;
            const int ra = row0 + rr, rb = row0 + 32 + rr;
            if (ra < Nx) rowpart[outb + ra] = v0;
            if (rb < Nx) rowpart[outb + rb] = v1;
        }
    }
}

__global__ __launch_bounds__(256) void combine_kernel(
    const float* __restrict__ rowpart, int B, int N, int M,
    int NpadP, int NpadT, int NpadMax,
    float invBN, float invBM, float* __restrict__ partial)
{
    const int tid = threadIdx.x;
    const int tot = 2 * B * NpadMax;
    float acc = 0.f;
    for (int idx = blockIdx.x * 256 + tid; idx < tot; idx += gridDim.x * 256) {
        const int row = idx % NpadMax;
        const int rem = idx / NpadMax;
        const int b   = rem % B;
        const int dir = rem / B;
        const int Nx  = (dir == 0) ? N : M;
        if (row >= Nx) continue;
        float m = __builtin_inff();
        #pragma unroll
        for (int js = 0; js < YS; ++js)
            m = fminf(m, rowpart[(((size_t)dir * B + b) * YS + js)
                                 * (size_t)NpadMax + row]);
        acc += fmaxf(m, 0.f) * ((dir == 0) ? invBN : invBM);
    }
    __shared__ float sb[256];
    sb[tid] = acc; __syncthreads();
    for (int off2 = 128; off2 > 0; off2 >>= 1) {
        if (tid < off2) sb[tid] += sb[tid + off2];
        __syncthreads();
    }
    if (tid == 0) partial[blockIdx.x] = sb[0];
}

__global__ void finalize_kernel(const float* __restrict__ partial, int np,
                                const float* __restrict__ fbpp, int Bf,
                                const void* __restrict__ lamp,
                                float* __restrict__ out)
{
    __shared__ float sb[256];
    const int tid = threadIdx.x;
    float acc = 0.f;
    for (int i = tid; i < np; i += 256) acc += partial[i];
    sb[tid] = acc;
    __syncthreads();
    for (int off = 128; off > 0; off >>= 1) {
        if (tid < off) sb[tid] += sb[tid + off];
        __syncthreads();
    }
    if (tid == 0) {
        const int li = *(const int*)lamp;
        const float lam = (li >= -1000000 && li <= 1000000)
                            ? (float)li : *(const float*)lamp;
        float fm = 0.f;
        for (int i = 0; i < Bf; ++i) fm += fbpp[i];
        fm /= (float)Bf;
        out[0] = sb[0] + lam * fm;
    }
}

extern "C" void kernel_launch(void* const* d_in, const int* in_sizes, int n_in,
                              void* d_out, int out_size, void* d_ws, size_t ws_size,
                              hipStream_t stream) {
    const float* pred = (const float*)d_in[0];
    const float* targ = (const float*)d_in[1];
    const float* fbpp = (const float*)d_in[2];
    const void*  lamp = d_in[3];

    const int B = in_sizes[2];
    const int N = in_sizes[0] / (3 * B);
    const int M = in_sizes[1] / (3 * B);
    const int NpadP = roundup_h(N, RPB);
    const int NpadT = roundup_h(M, RPB);
    const int NpadMax = (NpadP > NpadT) ? NpadP : NpadT;

    // ---- workspace layout (+8KB slack after each pack for prefetch OOB) ----
    size_t o = 0;
    auto take = [&](size_t bytes) {
        size_t r = o; o += (bytes + 255) & ~(size_t)255; return r;
    };
    unsigned short* aP = (unsigned short*)((char*)d_ws +
                         take((size_t)B * NpadP * 32 + 8192));
    unsigned short* bP = (unsigned short*)((char*)d_ws +
                         take((size_t)B * NpadP * 32 + 8192));
    unsigned short* aT = (unsigned short*)((char*)d_ws +
                         take((size_t)B * NpadT * 32 + 8192));
    unsigned short* bT = (unsigned short*)((char*)d_ws +
                         take((size_t)B * NpadT * 32 + 8192));
    float* rowpart = (float*)((char*)d_ws +
                     take((size_t)2 * B * YS * NpadMax * sizeof(float)));
    float* partial = (float*)((char*)d_ws + take(256 * sizeof(float)));
    (void)ws_size;

    // ---- 1) pack both clouds into A/B MFMA K-patterns ----
    pack_kernel<<<(B * NpadMax + 255) / 256, 256, 0, stream>>>(
        pred, targ, B, N, M, NpadP, NpadT, aP, bP, aT, bT);

    // ---- 2) MFMA pair sweep (both directions) ----
    const int SP = NpadMax / RPB;
    const int blocks = 2 * B * YS * SP;
    mfma_sweep<<<blocks, 256, 0, stream>>>(
        aP, bP, aT, bT, B, N, M, NpadP, NpadT, NpadMax, rowpart);

    // ---- 3) combine splits + clamp + weighted sum ----
    combine_kernel<<<256, 256, 0, stream>>>(
        rowpart, B, N, M, NpadP, NpadT, NpadMax,
        1.f / ((float)B * (float)N), 1.f / ((float)B * (float)M), partial);

    // ---- 4) finalize ----
    finalize_kernel<<<1, 256, 0, stream>>>(partial, 256, fbpp, B, lamp,
                                           (float*)d_out);
}